// Round 1
// baseline (507.155 us; speedup 1.0000x reference)
//
#include <hip/hip_runtime.h>
#include <stdint.h>

typedef __bf16 bf16;
typedef __attribute__((ext_vector_type(8))) bf16 bf16x8;
typedef __attribute__((ext_vector_type(4))) float f32x4;

#define D 64
#define DIN 192

__device__ __forceinline__ float silu_f(float x) {
    return x / (1.0f + __expf(-x));
}

// ---------------------------------------------------------------------------
// Phase 1: per-edge message MLP (bf16 MFMA) + atomic scatter-add into agg
//   msg = (silu([nf[src], nf[dst], ef] @ W1 + b1)) @ W2 + b2
//   agg[dst] += msg
// Tile = 64 edges. Block = 256 threads = 4 waves; wave w owns edge rows
// 16w..16w+15 (M-split). K-slot convention k' = 32*ks + 8*(lane>>4) + i is
// used for BOTH A and B fragments -> self-consistent regardless of the HW's
// internal k permutation. C/D layout: col = lane&15, row = 4*(lane>>4)+reg.
// ---------------------------------------------------------------------------
__launch_bounds__(256, 2)
__global__ void mp_edge_kernel(
    const float* __restrict__ node_feat,
    const int*   __restrict__ esrc,
    const int*   __restrict__ edst,
    const float* __restrict__ efeat,
    const float* __restrict__ W1, const float* __restrict__ b1,
    const float* __restrict__ W2, const float* __restrict__ b2,
    float* __restrict__ agg,
    int E, int ntiles)
{
    // B fragments pre-arranged so lane l reads 16B at [entry*8]: conflict-free
    __shared__ __align__(16) bf16 W1f[6*4*64*8];   // 24.0 KB  (ks, nt, lane, 8)
    __shared__ __align__(16) bf16 W2f[2*4*64*8];   //  8.0 KB
    __shared__ __align__(16) bf16 Xs[64*200];      // 25.6 KB  rows padded: stride 200
    __shared__ __align__(16) bf16 Hs[64*72];       //  9.2 KB  stride 72
    __shared__ float b1s[D], b2s[D];
    __shared__ int   dsts[64];

    const int t    = threadIdx.x;
    const int lane = t & 63;
    const int w    = t >> 6;        // wave 0..3
    const int g    = lane >> 4;     // k-group 0..3
    const int c    = lane & 15;

    // ---- stage W1/W2 as MFMA B-fragments (once per block) ----
    for (int idx = t; idx < 6*4*64; idx += 256) {
        int l = idx & 63, nt = (idx >> 6) & 3, ks = idx >> 8;
        int k0 = ks*32 + (l >> 4)*8, col = nt*16 + (l & 15);
        bf16x8 v;
        #pragma unroll
        for (int i = 0; i < 8; ++i) v[i] = (bf16)W1[(k0 + i)*D + col];
        *(bf16x8*)&W1f[idx*8] = v;
    }
    for (int idx = t; idx < 2*4*64; idx += 256) {
        int l = idx & 63, nt = (idx >> 6) & 3, ks = idx >> 8;
        int k0 = ks*32 + (l >> 4)*8, col = nt*16 + (l & 15);
        bf16x8 v;
        #pragma unroll
        for (int i = 0; i < 8; ++i) v[i] = (bf16)W2[(k0 + i)*D + col];
        *(bf16x8*)&W2f[idx*8] = v;
    }
    if (t < D) { b1s[t] = b1[t]; b2s[t] = b2[t]; }

    for (int tile = blockIdx.x; tile < ntiles; tile += gridDim.x) {
        __syncthreads();  // weights staged / previous tile's Xs,Hs,dsts readers done

        // ---- gather + convert X tile: [64 edges][192] bf16 ----
        const int erow = t >> 2, q = t & 3;       // 4 threads per edge row
        const int eidx = tile*64 + erow;
        const bool valid = eidx < E;
        const int eload = valid ? eidx : 0;
        const int se = esrc[eload];
        const int de = edst[eload];
        if (q == 0) dsts[erow] = de;
        const float* srcp[3] = { node_feat + (size_t)se*D,
                                 node_feat + (size_t)de*D,
                                 efeat + (size_t)eload*D };
        #pragma unroll
        for (int s = 0; s < 3; ++s) {
            const float* p = srcp[s] + q*16;
            f32x4 v0 = ((const f32x4*)p)[0];
            f32x4 v1 = ((const f32x4*)p)[1];
            f32x4 v2 = ((const f32x4*)p)[2];
            f32x4 v3 = ((const f32x4*)p)[3];
            bf16x8 o0, o1;
            #pragma unroll
            for (int i = 0; i < 4; ++i) {
                o0[i]   = (bf16)v0[i];  o0[4+i] = (bf16)v1[i];
                o1[i]   = (bf16)v2[i];  o1[4+i] = (bf16)v3[i];
            }
            *(bf16x8*)&Xs[erow*200 + s*64 + q*16]     = o0;
            *(bf16x8*)&Xs[erow*200 + s*64 + q*16 + 8] = o1;
        }
        __syncthreads();

        // ---- GEMM1: [16,192]@[192,64] per wave ----
        f32x4 acc[4] = {f32x4{0,0,0,0}, f32x4{0,0,0,0}, f32x4{0,0,0,0}, f32x4{0,0,0,0}};
        #pragma unroll
        for (int ks = 0; ks < 6; ++ks) {
            bf16x8 a = *(const bf16x8*)&Xs[(w*16 + c)*200 + ks*32 + g*8];
            #pragma unroll
            for (int nt = 0; nt < 4; ++nt) {
                bf16x8 bb = *(const bf16x8*)&W1f[((ks*4 + nt)*64 + lane)*8];
                acc[nt] = __builtin_amdgcn_mfma_f32_16x16x32_bf16(a, bb, acc[nt], 0, 0, 0);
            }
        }

        // ---- bias + SiLU -> Hs (bf16) ----
        #pragma unroll
        for (int nt = 0; nt < 4; ++nt) {
            int col = nt*16 + c;
            float bias = b1s[col];
            #pragma unroll
            for (int j = 0; j < 4; ++j) {
                float v = acc[nt][j] + bias;
                Hs[(w*16 + g*4 + j)*72 + col] = (bf16)silu_f(v);
            }
        }
        __syncthreads();  // conservative: Hs write->read ordering across lanes

        // ---- GEMM2: [16,64]@[64,64] per wave ----
        f32x4 acc2[4] = {f32x4{0,0,0,0}, f32x4{0,0,0,0}, f32x4{0,0,0,0}, f32x4{0,0,0,0}};
        #pragma unroll
        for (int ks = 0; ks < 2; ++ks) {
            bf16x8 a = *(const bf16x8*)&Hs[(w*16 + c)*72 + ks*32 + g*8];
            #pragma unroll
            for (int nt = 0; nt < 4; ++nt) {
                bf16x8 bb = *(const bf16x8*)&W2f[((ks*4 + nt)*64 + lane)*8];
                acc2[nt] = __builtin_amdgcn_mfma_f32_16x16x32_bf16(a, bb, acc2[nt], 0, 0, 0);
            }
        }

        // ---- bias + atomic scatter-add ----
        #pragma unroll
        for (int nt = 0; nt < 4; ++nt) {
            int col = nt*16 + c;
            float bias = b2s[col];
            #pragma unroll
            for (int j = 0; j < 4; ++j) {
                int row = w*16 + g*4 + j;
                if (tile*64 + row < E) {
                    atomicAdd(&agg[(size_t)dsts[row]*D + col], acc2[nt][j] + bias);
                }
            }
        }
    }
}

// ---------------------------------------------------------------------------
// Phase 2: per-node update MLP (fp32) + residual + LayerNorm, in-place on agg.
// One wave per node; lane j owns output dim j; k-broadcast via __shfl.
// ---------------------------------------------------------------------------
__launch_bounds__(256, 4)
__global__ void mp_node_kernel(
    const float* __restrict__ node_feat,
    const float* __restrict__ Wu1, const float* __restrict__ bu1,
    const float* __restrict__ Wu2, const float* __restrict__ bu2,
    const float* __restrict__ gamma, const float* __restrict__ beta,
    float* __restrict__ inout,     // agg on entry, final output on exit
    int nnodes)
{
    __shared__ __align__(16) float W1t[64*68];   // transposed [j][k], stride 68
    __shared__ __align__(16) float W2t[64*68];
    __shared__ float b1s[D], b2s[D], gs[D], bs[D];

    const int t = threadIdx.x, lane = t & 63, w = t >> 6;
    for (int idx = t; idx < 4096; idx += 256) {
        int j = idx & 63, k = idx >> 6;          // coalesced global reads
        W1t[j*68 + k] = Wu1[k*D + j];
        W2t[j*68 + k] = Wu2[k*D + j];
    }
    if (t < D) { b1s[t] = bu1[t]; b2s[t] = bu2[t]; gs[t] = gamma[t]; bs[t] = beta[t]; }
    __syncthreads();

    for (int n = blockIdx.x*4 + w; n < nnodes; n += gridDim.x*4) {
        float a  = inout[(size_t)n*D + lane];
        float x0 = node_feat[(size_t)n*D + lane];

        float acc = b1s[lane];
        #pragma unroll
        for (int k4 = 0; k4 < 16; ++k4) {
            f32x4 wv = *(const f32x4*)&W1t[lane*68 + k4*4];
            acc += __shfl(a, k4*4+0)*wv[0] + __shfl(a, k4*4+1)*wv[1]
                 + __shfl(a, k4*4+2)*wv[2] + __shfl(a, k4*4+3)*wv[3];
        }
        float h = silu_f(acc);

        float acc2 = b2s[lane];
        #pragma unroll
        for (int k4 = 0; k4 < 16; ++k4) {
            f32x4 wv = *(const f32x4*)&W2t[lane*68 + k4*4];
            acc2 += __shfl(h, k4*4+0)*wv[0] + __shfl(h, k4*4+1)*wv[1]
                  + __shfl(h, k4*4+2)*wv[2] + __shfl(h, k4*4+3)*wv[3];
        }

        float y = x0 + acc2;
        float s1 = y, s2 = y*y;
        #pragma unroll
        for (int off = 32; off > 0; off >>= 1) {
            s1 += __shfl_xor(s1, off);
            s2 += __shfl_xor(s2, off);
        }
        float mu  = s1 * (1.0f/64.0f);
        float var = s2 * (1.0f/64.0f) - mu*mu;
        float rs  = rsqrtf(var + 1e-5f);
        inout[(size_t)n*D + lane] = (y - mu)*rs*gs[lane] + bs[lane];
    }
}

extern "C" void kernel_launch(void* const* d_in, const int* in_sizes, int n_in,
                              void* d_out, int out_size, void* d_ws, size_t ws_size,
                              hipStream_t stream) {
    const float* node_feat = (const float*)d_in[0];
    const int*   esrc      = (const int*)d_in[1];
    const int*   edst      = (const int*)d_in[2];
    const float* efeat     = (const float*)d_in[3];
    const float* W_m1      = (const float*)d_in[4];
    const float* b_m1      = (const float*)d_in[5];
    const float* W_m2      = (const float*)d_in[6];
    const float* b_m2      = (const float*)d_in[7];
    const float* W_u1      = (const float*)d_in[8];
    const float* b_u1      = (const float*)d_in[9];
    const float* W_u2      = (const float*)d_in[10];
    const float* b_u2      = (const float*)d_in[11];
    const float* ln_gamma  = (const float*)d_in[12];
    const float* ln_beta   = (const float*)d_in[13];

    float* out = (float*)d_out;
    const int E      = in_sizes[1];
    const int nnodes = in_sizes[0] / D;

    // agg accumulates directly into d_out; phase 2 rewrites it in place
    hipMemsetAsync(out, 0, (size_t)nnodes * D * sizeof(float), stream);

    const int ntiles = (E + 63) / 64;
    const int grid1  = ntiles < 2048 ? ntiles : 2048;
    mp_edge_kernel<<<grid1, 256, 0, stream>>>(node_feat, esrc, edst, efeat,
                                              W_m1, b_m1, W_m2, b_m2,
                                              out, E, ntiles);

    mp_node_kernel<<<2048, 256, 0, stream>>>(node_feat, W_u1, b_u1, W_u2, b_u2,
                                             ln_gamma, ln_beta, out, nnodes);
}